// Round 2
// 10006.198 us; speedup vs baseline: 1.1064x; 1.1064x over previous
//
#include <hip/hip_runtime.h>

// Persistent wavefront-pipelined LSTMP (3 layers), split-bf16 MFMA emulating fp32.
// Round 5: REGISTER-RESIDENT WEIGHTS. The split-bf16 gate + proj weights were
// re-streamed from L2/LIC/HBM every step (~50 MB/step, 31 MB/step missing to HBM
// = FETCH_SIZE 15.25 GB, step period ~= weight refetch time). Weights are
// constant, roles are fixed -> hold each wave's slice in VGPRs for all 500 steps:
//   phase A: wgh/wgl[4][4] s16x8 = 128 VGPRs, phase C: wph/wpl[4] = 32 VGPRs.
// __launch_bounds__(512,2) caps at 256 VGPR/wave (2 waves/SIMD, 1 block/CU).
// Pointwise bias/peephole constants also hoisted to 7 VGPRs/thread.
// Exchange (h/m) unchanged: relaxed agent-scope atomics + m-flags + 1 gbar/step.

typedef short s16x4 __attribute__((ext_vector_type(4)));
typedef short s16x8 __attribute__((ext_vector_type(8)));
typedef float f32x4 __attribute__((ext_vector_type(4)));

#define MFMA16(a,b,c) __builtin_amdgcn_mfma_f32_16x16x32_bf16((a),(b),(c),0,0,0)

__device__ __forceinline__ unsigned short f2bf(float f) {
  unsigned int u = __builtin_bit_cast(unsigned int, f);
  u += 0x7FFFu + ((u >> 16) & 1u);          // RNE
  return (unsigned short)(u >> 16);
}
__device__ __forceinline__ float bf2f(unsigned short h) {
  unsigned int u = ((unsigned int)h) << 16;
  return __builtin_bit_cast(float, u);
}
__device__ __forceinline__ float fsig(float x)  { return __fdividef(1.0f, 1.0f + __expf(-x)); }
__device__ __forceinline__ float ftanh(float x) { return 1.0f - __fdividef(2.0f, 1.0f + __expf(2.0f * x)); }

// Coherent (LIC) 16B read as two relaxed agent-scope 8B atomic loads.
__device__ __forceinline__ s16x8 cload(const unsigned short* p) {
  unsigned long long a = __hip_atomic_load((unsigned long long*)p,       __ATOMIC_RELAXED, __HIP_MEMORY_SCOPE_AGENT);
  unsigned long long b = __hip_atomic_load((unsigned long long*)(p + 4), __ATOMIC_RELAXED, __HIP_MEMORY_SCOPE_AGENT);
  s16x4 x = __builtin_bit_cast(s16x4, a);
  s16x4 y = __builtin_bit_cast(s16x4, b);
  s16x8 r = {x[0], x[1], x[2], x[3], y[0], y[1], y[2], y[3]};
  return r;
}
__device__ __forceinline__ void cstore1(unsigned short* p, unsigned short v) {
  __hip_atomic_store(p, v, __ATOMIC_RELAXED, __HIP_MEMORY_SCOPE_AGENT);
}

// Relaxed sense-counting grid barrier (192 blocks, 512 threads).
__device__ __forceinline__ void gbar(unsigned int* bar, unsigned int* rel, unsigned int seq) {
  __syncthreads();
  asm volatile("" ::: "memory");
  if (blockIdx.x == 0) {
    const int tid = threadIdx.x;
    if (tid > 0 && tid < 192) {
      while (__hip_atomic_load(&bar[tid * 16], __ATOMIC_RELAXED, __HIP_MEMORY_SCOPE_AGENT) != seq) {
        __builtin_amdgcn_s_sleep(1);
      }
    }
    __syncthreads();
    if (tid == 0) {
      __hip_atomic_store(rel, seq, __ATOMIC_RELAXED, __HIP_MEMORY_SCOPE_AGENT);
    }
  } else {
    if (threadIdx.x == 0) {
      __hip_atomic_store(&bar[blockIdx.x * 16], seq, __ATOMIC_RELAXED, __HIP_MEMORY_SCOPE_AGENT);
      while (__hip_atomic_load(rel, __ATOMIC_RELAXED, __HIP_MEMORY_SCOPE_AGENT) != seq) {
        __builtin_amdgcn_s_sleep(1);
      }
    }
    __syncthreads();
  }
  asm volatile("" ::: "memory");
}

__global__ __launch_bounds__(512, 2) void lstmp_persist(
    const float* __restrict__ x,
    const float* __restrict__ W0, const float* __restrict__ b0, const float* __restrict__ P0,
    const float* __restrict__ pi0, const float* __restrict__ pf0, const float* __restrict__ po0,
    const float* __restrict__ W1, const float* __restrict__ b1, const float* __restrict__ P1,
    const float* __restrict__ pi1, const float* __restrict__ pf1, const float* __restrict__ po1,
    const float* __restrict__ W2, const float* __restrict__ b2, const float* __restrict__ P2,
    const float* __restrict__ pi2, const float* __restrict__ pf2, const float* __restrict__ po2,
    float* __restrict__ out, unsigned char* __restrict__ ws)
{
  const int tid  = threadIdx.x;
  const int bid  = blockIdx.x;
  const int lane = tid & 63;
  const int wv   = tid >> 6;             // 0..7
  const int quad8 = (lane >> 4) * 8;
  const int nrow  = lane & 15;

  // ---- workspace carve (weight staging regions no longer used) ----
  unsigned int* bar   = (unsigned int*)ws;   // 192 slots * 16 uints (within 4096)
  unsigned int* rel   = bar + 4096;
  unsigned int* mflag = rel + 16;            // 3*64 flags
  unsigned short* xhi = (unsigned short*)(ws + 20480);
  unsigned short* xlo  = xhi  + 4096000;   // 500*32*256
  unsigned short* hhi  = xlo  + 4096000;   // 2 bufs * 3*32*512
  unsigned short* hlo  = hhi  + 98304;
  unsigned short* mhi  = hlo  + 98304;     // 3*32*1024
  unsigned short* mlo  = mhi  + 98304;

  const float* Wsrc[3] = {W0, W1, W2};
  const float* Psrc[3] = {P0, P1, P2};
  const float* Bsrc[3] = {b0, b1, b2};
  const float* PIs[3]  = {pi0, pi1, pi2};
  const float* PFs[3]  = {pf0, pf1, pf2};
  const float* POs[3]  = {po0, po1, po2};

  __shared__ float exch[8][4][512];  // 64 KB: per-wave partial sums
  __shared__ float c_lds[512];       // persistent cell state
  __shared__ float lds_pad[4096];    // 16 KB pad -> 82 KB total -> 1 block/CU
  ((volatile float*)lds_pad)[tid & 4095] = 0.0f;  // keep it allocated

  const unsigned int NT = 192u * 512u;
  const unsigned int gtid = (unsigned int)bid * 512u + (unsigned int)tid;

  // ---- fixed per-block roles (grid = 192, all workers) ----
  const int lA  = bid >> 6;          // layer 0..2
  const int utA = bid & 63;          // 16-unit tile (phase A)
  const int ptC = (bid & 63) >> 1;   // proj 16-col tile (phase C)
  const int mtC = bid & 1;           // batch half (phase C)

  const int nkbinA  = (lA == 0) ? 8   : 16;
  const int kinpadA = (lA == 0) ? 256 : 512;
  const int kbwA    = (lA == 0) ? 3   : 4;    // k-blocks per wave
  const int kwA     = (lA == 0) ? 752 : 1024;
  const int ninA    = (lA == 0) ? 240 : 512;
  const int kb0     = wv * kbwA;

  // ================= INIT: x staging + h zero =================
  for (unsigned int i = gtid; i < 4096000u; i += NT) {
    unsigned int k = i & 255u, tb = i >> 8;
    float v = (k < 240u) ? x[tb * 240u + k] : 0.0f;
    unsigned short h = f2bf(v);
    xhi[i] = h; xlo[i] = f2bf(v - bf2f(h));
  }
  for (unsigned int i = gtid; i < 98304u; i += NT) { hhi[i] = 0; hlo[i] = 0; }
  c_lds[tid] = 0.0f;

  // ================= register-resident weights =================
  // Phase A gate weights: per wave kbwA(<=4) kb-blocks x 4 gate groups, hi+lo.
  // Fragment for lane: W row (g*64+utA)*16 + nrow, k = kb*32 + quad8 + jj.
  s16x8 wgh[4][4], wgl[4][4];
  {
    const float* Wl = Wsrc[lA];
    #pragma unroll
    for (int j = 0; j < 4; ++j) {
      if (j < kbwA) {
        const int kbase = (kb0 + j) * 32 + quad8;
        #pragma unroll
        for (int g = 0; g < 4; ++g) {
          const size_t r = (size_t)((g * 64 + utA) * 16 + nrow);
          #pragma unroll
          for (int jj = 0; jj < 8; ++jj) {
            const int k = kbase + jj;
            float v;
            if (k < kinpadA) v = (lA == 0 && k >= 240) ? 0.0f : Wl[r * kwA + k];
            else             v = Wl[r * kwA + (k - kinpadA + ninA)];
            unsigned short h = f2bf(v);
            wgh[j][g][jj] = (short)h;
            wgl[j][g][jj] = (short)f2bf(v - bf2f(h));
          }
        }
      } else {
        #pragma unroll
        for (int g = 0; g < 4; ++g) { wgh[j][g] = (s16x8)0; wgl[j][g] = (s16x8)0; }
      }
    }
  }
  // Phase C proj weights: per wave 4 kb-blocks, hi+lo.
  s16x8 wph[4], wpl[4];
  {
    const float* Pl = Psrc[lA];
    const size_t prow = (size_t)(ptC * 16 + nrow);
    #pragma unroll
    for (int j = 0; j < 4; ++j) {
      const int kbase = (wv * 4 + j) * 32 + quad8;
      #pragma unroll
      for (int jj = 0; jj < 8; ++jj) {
        float v = Pl[prow * 1024u + (size_t)(kbase + jj)];
        unsigned short h = f2bf(v);
        wph[j][jj] = (short)h;
        wpl[j][jj] = (short)f2bf(v - bf2f(h));
      }
    }
  }
  // Pointwise constants: this thread always handles (b=tid>>4, u=tid&15).
  const int uc = utA * 16 + (tid & 15);
  const float rbc = Bsrc[lA][uc];
  const float rbi = Bsrc[lA][1024 + uc];
  const float rbf = Bsrc[lA][2048 + uc];
  const float rbo = Bsrc[lA][3072 + uc];
  const float rpi = PIs[lA][uc];
  const float rpf = PFs[lA][uc];
  const float rpo = POs[lA][uc];

  unsigned int seq = 1;
  __builtin_amdgcn_fence(__ATOMIC_RELEASE, "agent");
  gbar(bar, rel, seq++);
  __builtin_amdgcn_fence(__ATOMIC_ACQUIRE, "agent");

  for (int s = 0; s < 502; ++s) {
    const int t = s - lA;
    const bool act = (t >= 0) && (t < 500);
    const int rbuf = (s + 1) & 1;    // h buffer written at step s-1
    const int wbuf = s & 1;          // h buffer written at step s

    if (act) {
      // ============ PHASE A: gates GEMM (8 waves split K, reg weights) ============
      f32x4 acc[4][2];
      #pragma unroll
      for (int g = 0; g < 4; ++g) { acc[g][0] = {0.f,0.f,0.f,0.f}; acc[g][1] = {0.f,0.f,0.f,0.f}; }

      const unsigned short* hbh = hhi + rbuf * 49152;
      const unsigned short* hbl = hlo + rbuf * 49152;

      #pragma unroll
      for (int j = 0; j < 4; ++j) {
        if (j < kbwA) {
          const int kb = kb0 + j;
          s16x8 fa0h, fa0l, fa1h, fa1l;
          if (kb < nkbinA) {
            if (lA == 0) {
              const unsigned short* ph = xhi + (size_t)(t * 32 + nrow) * 256 + kb * 32 + quad8;
              const unsigned short* pl = xlo + (size_t)(t * 32 + nrow) * 256 + kb * 32 + quad8;
              fa0h = *(const s16x8*)ph; fa1h = *(const s16x8*)(ph + 16 * 256);
              fa0l = *(const s16x8*)pl; fa1l = *(const s16x8*)(pl + 16 * 256);
            } else {
              const unsigned short* ph = hbh + (size_t)((lA - 1) * 32 + nrow) * 512 + kb * 32 + quad8;
              const unsigned short* pl = hbl + (size_t)((lA - 1) * 32 + nrow) * 512 + kb * 32 + quad8;
              fa0h = cload(ph); fa1h = cload(ph + 16 * 512);
              fa0l = cload(pl); fa1l = cload(pl + 16 * 512);
            }
          } else {
            const int ko = kb * 32 + quad8 - kinpadA;
            const unsigned short* ph = hbh + (size_t)(lA * 32 + nrow) * 512 + ko;
            const unsigned short* pl = hbl + (size_t)(lA * 32 + nrow) * 512 + ko;
            fa0h = cload(ph); fa1h = cload(ph + 16 * 512);
            fa0l = cload(pl); fa1l = cload(pl + 16 * 512);
          }
          #pragma unroll
          for (int g = 0; g < 4; ++g) {
            acc[g][0] = MFMA16(fa0h, wgh[j][g], acc[g][0]);
            acc[g][0] = MFMA16(fa0l, wgh[j][g], acc[g][0]);
            acc[g][0] = MFMA16(fa0h, wgl[j][g], acc[g][0]);
            acc[g][1] = MFMA16(fa1h, wgh[j][g], acc[g][1]);
            acc[g][1] = MFMA16(fa1l, wgh[j][g], acc[g][1]);
            acc[g][1] = MFMA16(fa1h, wgl[j][g], acc[g][1]);
          }
        }
      }
      #pragma unroll
      for (int g = 0; g < 4; ++g) {
        #pragma unroll
        for (int r = 0; r < 4; ++r) {
          const int m0 = (lane >> 4) * 4 + r;
          exch[wv][g][m0 * 16 + (lane & 15)]        = acc[g][0][r];
          exch[wv][g][(m0 + 16) * 16 + (lane & 15)] = acc[g][1][r];
        }
      }
      __syncthreads();

      // ---- fused pointwise: 512 threads, 1 (b,u) each, constants in regs ----
      {
        const int e = tid, b = tid >> 4;
        float sc = 0.f, si = 0.f, sf = 0.f, so = 0.f;
        #pragma unroll
        for (int w = 0; w < 8; ++w) {
          sc += exch[w][0][e]; si += exch[w][1][e];
          sf += exch[w][2][e]; so += exch[w][3][e];
        }
        const float cin = sc + rbc;
        const float gi  = si + rbi;
        const float gf  = sf + rbf;
        const float go  = so + rbo;
        const float cx  = c_lds[e];
        const float ig  = fsig(gi + rpi * cx);
        const float fg  = fsig(gf + rpf * cx);
        float cy = fg * cx + ig * ftanh(cin);
        cy = fminf(50.0f, fmaxf(-50.0f, cy));
        const float og = fsig(go + rpo * cy);
        const float mv = og * ftanh(cy);
        c_lds[e] = cy;
        const unsigned short mh = f2bf(mv);
        const size_t mi = (size_t)(lA * 32 + b) * 1024 + uc;
        cstore1(mhi + mi, mh);
        cstore1(mlo + mi, f2bf(mv - bf2f(mh)));
      }
      __syncthreads();   // drains each wave's vm stores before flag
      if (tid == 0) {
        __hip_atomic_store(&mflag[lA * 64 + utA], (unsigned int)(s + 1),
                           __ATOMIC_RELAXED, __HIP_MEMORY_SCOPE_AGENT);
      }

      // ============ PHASE C: projection (8 waves split K, reg weights) ============
      // wait for all 64 m-producers of this layer
      if (wv == 0) {
        const unsigned int want = (unsigned int)(s + 1);
        const unsigned int* fp = mflag + lA * 64 + lane;
        while (__hip_atomic_load(fp, __ATOMIC_RELAXED, __HIP_MEMORY_SCOPE_AGENT) != want) {
          __builtin_amdgcn_s_sleep(1);
        }
      }
      __syncthreads();

      const unsigned short* mah = mhi + (size_t)(lA * 32 + mtC * 16 + nrow) * 1024;
      const unsigned short* mal = mlo + (size_t)(lA * 32 + mtC * 16 + nrow) * 1024;
      f32x4 pacc = {0.f, 0.f, 0.f, 0.f};
      #pragma unroll
      for (int j = 0; j < 4; ++j) {
        const int ko = (wv * 4 + j) * 32 + quad8;
        s16x8 fah = cload(mah + ko);
        s16x8 fal = cload(mal + ko);
        pacc = MFMA16(fah, wph[j], pacc);
        pacc = MFMA16(fal, wph[j], pacc);
        pacc = MFMA16(fah, wpl[j], pacc);
      }
      #pragma unroll
      for (int r = 0; r < 4; ++r) {
        exch[wv][0][((lane >> 4) * 4 + r) * 16 + (lane & 15)] = pacc[r];
      }
      __syncthreads();
      if (tid < 256) {
        float v = 0.f;
        #pragma unroll
        for (int w = 0; w < 8; ++w) v += exch[w][0][tid];
        const int b = mtC * 16 + (tid >> 4);
        const int p = ptC * 16 + (tid & 15);
        const size_t hidx = (size_t)wbuf * 49152 + (size_t)(lA * 32 + b) * 512 + p;
        const unsigned short hh = f2bf(v);
        cstore1(hhi + hidx, hh);
        cstore1(hlo + hidx, f2bf(v - bf2f(hh)));
        if (lA == 2) out[((size_t)t * 32 + b) * 512 + p] = v;
      }
    }
    gbar(bar, rel, seq++);
  }
}

extern "C" void kernel_launch(void* const* d_in, const int* in_sizes, int n_in,
                              void* d_out, int out_size, void* d_ws, size_t ws_size,
                              hipStream_t stream) {
  const float* x   = (const float*)d_in[0];
  const float* W0  = (const float*)d_in[1];
  const float* b0  = (const float*)d_in[2];
  const float* P0  = (const float*)d_in[3];
  const float* pi0 = (const float*)d_in[4];
  const float* pf0 = (const float*)d_in[5];
  const float* po0 = (const float*)d_in[6];
  const float* W1  = (const float*)d_in[7];
  const float* b1  = (const float*)d_in[8];
  const float* P1  = (const float*)d_in[9];
  const float* pi1 = (const float*)d_in[10];
  const float* pf1 = (const float*)d_in[11];
  const float* po1 = (const float*)d_in[12];
  const float* P2_ = nullptr; (void)P2_;
  const float* W2  = (const float*)d_in[13];
  const float* b2  = (const float*)d_in[14];
  const float* P2  = (const float*)d_in[15];
  const float* pi2 = (const float*)d_in[16];
  const float* pf2 = (const float*)d_in[17];
  const float* po2 = (const float*)d_in[18];

  hipLaunchKernelGGL(lstmp_persist, dim3(192), dim3(512), 0, stream,
                     x, W0, b0, P0, pi0, pf0, po0,
                     W1, b1, P1, pi1, pf1, po1,
                     W2, b2, P2, pi2, pf2, po2,
                     (float*)d_out, (unsigned char*)d_ws);
}